// Round 7
// baseline (381.831 us; speedup 1.0000x reference)
//
#include <hip/hip_runtime.h>
#include <hip/hip_bf16.h>
#include <math.h>

// Problem constants (reference: B=8, S=1024, D=1024, E=8, F=2048, capacity 2 -> k=256)
#define B_   8
#define S_   1024
#define D_   1024
#define E_   8
#define F_   2048
#define KCAP 256

typedef __bf16 bf16x8 __attribute__((ext_vector_type(8)));
typedef float  floatx4 __attribute__((ext_vector_type(4)));
typedef unsigned short ushortx8 __attribute__((ext_vector_type(8)));

// ---- fp32 -> bf16 round-to-nearest-even (no NaN in this data) ----
__device__ __forceinline__ unsigned short f2b(float f) {
    union { float f; unsigned int u; } v; v.f = f;
    unsigned int u = v.u;
    u += 0x7fffu + ((u >> 16) & 1u);
    return (unsigned short)(u >> 16);
}
__device__ __forceinline__ float b2f(unsigned short u) {
    union { unsigned int u; float f; } v; v.u = ((unsigned)u) << 16; return v.f;
}

__device__ __forceinline__ void gl_lds16(const void* g, void* l) {
    __builtin_amdgcn_global_load_lds(
        (const __attribute__((address_space(1))) void*)g,
        (__attribute__((address_space(3))) void*)l, 16, 0, 0);
}

// sortable key: probs > 0 so float bits are monotonic; secondary index asc
// (larger (1023-s) wins ties -> smaller s, matching lax.top_k).
__device__ __forceinline__ unsigned long long topk_key(float p, int s) {
    return (((unsigned long long)__float_as_uint(p)) << 10) | (unsigned)(S_ - 1 - s);
}

// ---------------- 1. router: logits + softmax (fp32) + fused x->bf16 cast (vectorized) ----------------
// probs layout: [B][E][S] (transposed for per-(b,e) top-k). One wave per token; lane owns 4 consecutive d.
__global__ void router_kernel(const float* __restrict__ x, const float* __restrict__ cw,
                              float* __restrict__ probs, unsigned short* __restrict__ xb) {
    int gid  = blockIdx.x * 256 + threadIdx.x;
    int wave = gid >> 6;
    int lane = gid & 63;
    int b = wave >> 10;                                // S_=1024
    int s = wave & (S_ - 1);
    const float* xrow = x + ((size_t)b * S_ + s) * D_;
    unsigned short* xbrow = xb + ((size_t)b * S_ + s) * D_;
    float acc[E_];
#pragma unroll
    for (int e = 0; e < E_; e++) acc[e] = 0.f;
#pragma unroll
    for (int it = 0; it < D_ / 256; it++) {
        int i = it * 256 + lane * 4;
        float4 xv = *(const float4*)(xrow + i);
        ushort4 o;
        o.x = f2b(xv.x); o.y = f2b(xv.y); o.z = f2b(xv.z); o.w = f2b(xv.w);
        *(ushort4*)(xbrow + i) = o;                    // fused cast, 8B/lane stores
#pragma unroll
        for (int e = 0; e < E_; e++) {
            float4 wv = *(const float4*)(cw + e * D_ + i);   // 32KB table, L1/L2-resident
            acc[e] = fmaf(xv.x, wv.x, fmaf(xv.y, wv.y, fmaf(xv.z, wv.z, fmaf(xv.w, wv.w, acc[e]))));
        }
    }
#pragma unroll
    for (int e = 0; e < E_; e++) {
        float v = acc[e];
#pragma unroll
        for (int off = 32; off >= 1; off >>= 1) v += __shfl_down(v, off, 64);
        acc[e] = v;
    }
    if (lane == 0) {
        float m = acc[0];
#pragma unroll
        for (int e = 1; e < E_; e++) m = fmaxf(m, acc[e]);
        float sum = 0.f;
#pragma unroll
        for (int e = 0; e < E_; e++) { acc[e] = __expf(acc[e] - m); sum += acc[e]; }
        float inv = 1.f / sum;
#pragma unroll
        for (int e = 0; e < E_; e++) probs[((size_t)b * E_ + e) * S_ + s] = acc[e] * inv;
    }
}

// ---------------- 2. prep: BOTH weight transposes + top-k in ONE launch (1D decode) ----------------
// BW-tuned transpose (round 6 measured the 32x32/4KB-per-block version at 1.44 TB/s,
// VALUBusy 10% -- latency-bound: 1 load in flight, 64B partial-line stores).
// New tile: 128 rows x 32 cols per block (24 KB moved): 4 independent float4 loads/thread,
// 2 ushort8 stores/thread, each out-row a full 256B contiguous run. LDS [128][33] fp32:
// write banks (r + 4*seg)%32 -> 2-way (free, m136); read banks (8*s8 + c)%32 -> 2-way (free).
// blocks [0, 4096)     : w1 [E][D][F] fp32 -> w1t [E][F][D] bf16   (R=D=1024, C=F=2048)
// blocks [4096, 8192)  : w2 [E][F][D] fp32 -> w2t [E][D][F] bf16   (R=F=2048, C=D=1024)
// blocks [8192, 8256)  : top-k for be = bid - 8192 (all-pairs rank; emits I, G, Pmap)
union PrepSm {
    float tile[128][33];                 // 16,896 B (transpose paths)
    unsigned long long keys[S_];         //  8,192 B (topk path)
};
__global__ void prep_kernel(const float* __restrict__ w1, const float* __restrict__ w2,
                            unsigned short* __restrict__ w1t, unsigned short* __restrict__ w2t,
                            const float* __restrict__ probs, int* __restrict__ I,
                            float* __restrict__ G, unsigned short* __restrict__ Pmap) {
    const int bid = blockIdx.x;
    const int tid = threadIdx.x;
    __shared__ PrepSm sm;

    if (bid >= 2 * 4096) {
        // ---- top-k path (identical math to verified merged topk) ----
        const int be = bid - 2 * 4096;                // 0..63
        const int b = be >> 3, e = be & 7;
        const float* rowp = probs + (size_t)be * S_;
#pragma unroll
        for (int q = 0; q < 4; q++) {
            const int s = q * 256 + tid;
            sm.keys[s] = topk_key(rowp[s], s);
            Pmap[((size_t)(b * S_ + s)) * E_ + e] = 0;
        }
        __syncthreads();
        unsigned long long my[4];
        int r[4] = {0, 0, 0, 0};
#pragma unroll
        for (int q = 0; q < 4; q++) my[q] = sm.keys[q * 256 + tid];
#pragma unroll 8
        for (int t = 0; t < S_; t++) {
            const unsigned long long kt = sm.keys[t]; // LDS broadcast
#pragma unroll
            for (int q = 0; q < 4; q++) r[q] += (kt > my[q]);
        }
#pragma unroll
        for (int q = 0; q < 4; q++) {
            if (r[q] < KCAP) {
                const int s = q * 256 + tid;
                I[be * KCAP + r[q]] = s;
                G[be * KCAP + r[q]] = rowp[s];
                Pmap[((size_t)(b * S_ + s)) * E_ + e] = (unsigned short)(r[q] + 1);
            }
        }
        return;
    }

    // ---- transpose+cast path ----
    const float* in;
    unsigned short* out;
    int R, C, e, c0, r0;
    if (bid < 4096) {
        in = w1; out = w1t; R = D_; C = F_;
        e = bid >> 9;                                 // 512 tiles/expert
        const int t = bid & 511;                      // 64 col-tiles x 8 row-tiles
        c0 = (t & 63) * 32; r0 = (t >> 6) * 128;
    } else {
        const int b2 = bid - 4096;
        in = w2; out = w2t; R = F_; C = D_;
        e = b2 >> 9;
        const int t = b2 & 511;                       // 32 col-tiles x 16 row-tiles
        c0 = (t & 31) * 32; r0 = (t >> 5) * 128;
    }
    const float* ine = in + (size_t)e * R * C;
    unsigned short* oute = out + (size_t)e * R * C;

    // load: 128 rows x 128B; thread (lrow, seg) loads rows lrow+{0,32,64,96}, 16B at col seg*4
    const int lrow = tid >> 3;                        // 0..31
    const int seg  = tid & 7;                         // 0..7
    float4 v[4];
#pragma unroll
    for (int i = 0; i < 4; i++)
        v[i] = *(const float4*)(ine + (size_t)(r0 + lrow + i * 32) * C + c0 + seg * 4);
#pragma unroll
    for (int i = 0; i < 4; i++) {
        const int rr = lrow + i * 32;
        sm.tile[rr][seg * 4 + 0] = v[i].x; sm.tile[rr][seg * 4 + 1] = v[i].y;
        sm.tile[rr][seg * 4 + 2] = v[i].z; sm.tile[rr][seg * 4 + 3] = v[i].w;
    }
    __syncthreads();

    // store: out-row c gets 128 bf16 = 16 ushort8; thread (c, k) writes segments k and k+8
    const int c = tid >> 3;                           // 0..31
    const int k = tid & 7;                            // 0..7
#pragma unroll
    for (int srep = 0; srep < 2; srep++) {
        const int s8 = k + srep * 8;                  // 0..15
        ushortx8 o;
#pragma unroll
        for (int j = 0; j < 8; j++) o[j] = f2b(sm.tile[s8 * 8 + j][c]);
        *(ushortx8*)(oute + (size_t)(c0 + c) * R + r0 + s8 * 8) = o;
    }
}

// ======== GEMM core notes (round-0 verified structure, ~880 TF) ========
// BK=64, 128x128 tile, 4 sweeps of 256 x 16B staging, bank-conflict-free via 16B-segment
// permutation seg_stored(c) = c ^ (row & 7) (verified: SQ_LDS_BANK_CONFLICT = 0).
// XCD swizzle: blockIdx % 8 selects e -> all tiles sharing w*t[e] on one XCD L2.
// NEGATIVE RESULTS (this session): 256^2 8-phase rewrite = 88 us / 32% Mfma vs 78 / 40%
// here (rounds 1-4); atomic-scatter combine fusion = +45 us on gemm2 (round 5; E*k/S = 2
// experts/token -> collisions are the norm). Launch-count reduction r0->r6 (8->5) = no
// wall change -> residual ~90 us is FIXED harness overhead; only kernel-sum matters.

// ---------------- 3. GEMM1: H[be] = silu(gather(x, I[be]) @ w1[e]) ----------------
__global__ __launch_bounds__(256, 4) void gemm1_kernel(
    const unsigned short* __restrict__ xb,   // [B][S][D] bf16
    const unsigned short* __restrict__ w1t,  // [E][F][D] bf16
    const int* __restrict__ I,               // [B][E][KCAP]
    unsigned short* __restrict__ H)          // [B*E][KCAP][F] bf16
{
    const int g  = blockIdx.x;               // 2048 = 8 xcd * 8 b * 32 tiles
    const int e  = g & 7;                    // XCD id
    const int rr = g >> 3;
    const int b  = rr >> 5;
    const int t5 = rr & 31;
    const int be = b * 8 + e;
    const int mt = t5 & 1;          // 2 m-tiles (256/128)
    const int nt = t5 >> 1;         // 16 n-tiles (2048/128)
    const int tid = threadIdx.x;

    __shared__ __align__(16) unsigned short Asm[128 * 64];  // 16 KB
    __shared__ __align__(16) unsigned short Bsm[128 * 64];  // 16 KB
    __shared__ unsigned int ArowS[128];

    if (tid < 128) {
        int tok = I[(size_t)be * KCAP + mt * 128 + tid];
        ArowS[tid] = (unsigned)((b * S_ + tok) * D_);
    }
    __syncthreads();

    const int r8   = tid >> 3;                       // 0..31 (row within sweep)
    const int kseg = (tid & 7) ^ (r8 & 7);           // permuted 16B segment
    unsigned aoffW[4];
#pragma unroll
    for (int w = 0; w < 4; w++) aoffW[w] = ArowS[w * 32 + r8] + kseg * 8;
    const size_t boff0 = ((size_t)e * F_ + nt * 128 + r8) * D_ + kseg * 8;

    const int lane = tid & 63;
    const int wv   = tid >> 6;
    const int wm   = (wv & 1) * 64;
    const int wn   = (wv >> 1) * 64;
    const int l15  = lane & 15;
    const int quad = lane >> 4;
    const int x0   = (quad ^ (l15 & 7)) * 8;         // h=0 swizzled seg offset (elements)

    int aoffs[4], boffs[4];
#pragma unroll
    for (int i = 0; i < 4; i++) {
        aoffs[i] = (wm + i * 16 + l15) * 64 + x0;
        boffs[i] = (wn + i * 16 + l15) * 64 + x0;
    }

    floatx4 acc[4][4];
#pragma unroll
    for (int i = 0; i < 4; i++)
#pragma unroll
        for (int j = 0; j < 4; j++) acc[i][j] = (floatx4){0.f, 0.f, 0.f, 0.f};

    for (int k0 = 0; k0 < D_; k0 += 64) {
#pragma unroll
        for (int w = 0; w < 4; w++) {
            gl_lds16(xb  + aoffW[w] + k0,                    &Asm[(w * 256 + tid) * 8]);
            gl_lds16(w1t + boff0 + (size_t)w * 32 * D_ + k0, &Bsm[(w * 256 + tid) * 8]);
        }
        __syncthreads();
        bf16x8 af[4], bfr[4];
#pragma unroll
        for (int i = 0; i < 4; i++) {                 // k-half 0
            af[i]  = *(const bf16x8*)&Asm[aoffs[i]];
            bfr[i] = *(const bf16x8*)&Bsm[boffs[i]];
        }
#pragma unroll
        for (int i = 0; i < 4; i++)
#pragma unroll
            for (int j = 0; j < 4; j++)
                acc[i][j] = __builtin_amdgcn_mfma_f32_16x16x32_bf16(af[i], bfr[j], acc[i][j], 0, 0, 0);
#pragma unroll
        for (int i = 0; i < 4; i++) {                 // k-half 1: seg offset = x0 ^ 4 -> elem ^ 32
            af[i]  = *(const bf16x8*)&Asm[aoffs[i] ^ 32];
            bfr[i] = *(const bf16x8*)&Bsm[boffs[i] ^ 32];
        }
#pragma unroll
        for (int i = 0; i < 4; i++)
#pragma unroll
            for (int j = 0; j < 4; j++)
                acc[i][j] = __builtin_amdgcn_mfma_f32_16x16x32_bf16(af[i], bfr[j], acc[i][j], 0, 0, 0);
        __syncthreads();
    }

    // epilogue: silu -> H (bf16). C/D layout: row = quad*4+r, col = lane&15 (m89-verified)
    unsigned short* Hbe = H + (size_t)be * KCAP * F_;
#pragma unroll
    for (int i = 0; i < 4; i++) {
#pragma unroll
        for (int r = 0; r < 4; r++) {
            int m = mt * 128 + wm + i * 16 + quad * 4 + r;
            unsigned short* hrow = Hbe + (size_t)m * F_ + nt * 128;
#pragma unroll
            for (int j = 0; j < 4; j++) {
                float v = acc[i][j][r];
                float sv = v / (1.f + __expf(-v));
                hrow[wn + j * 16 + l15] = f2b(sv);
            }
        }
    }
}

// ---------------- 4. GEMM2: xmlp[be] = H[be] @ w2[e]  (bf16 out, plain stores) ----------------
__global__ __launch_bounds__(256, 4) void gemm2_kernel(
    const unsigned short* __restrict__ H,    // [B*E][KCAP][F] bf16
    const unsigned short* __restrict__ w2t,  // [E][D][F] bf16
    unsigned short* __restrict__ xmlp)       // [B*E][KCAP][D] bf16
{
    const int g  = blockIdx.x;               // 1024 = 8 xcd * 8 b * 16 tiles
    const int e  = g & 7;                    // XCD id
    const int rr = g >> 3;
    const int b  = rr >> 4;
    const int t4 = rr & 15;
    const int be = b * 8 + e;
    const int mt = t4 & 1;          // 2 m-tiles
    const int nt = t4 >> 1;         // 8 n-tiles (1024/128)
    const int tid = threadIdx.x;

    __shared__ __align__(16) unsigned short Asm2[128 * 64];
    __shared__ __align__(16) unsigned short Bsm2[128 * 64];

    const int r8   = tid >> 3;
    const int kseg = (tid & 7) ^ (r8 & 7);
    const size_t aoff0 = ((size_t)be * KCAP + mt * 128 + r8) * F_ + kseg * 8;
    const size_t boff0 = ((size_t)e * D_ + nt * 128 + r8) * F_ + kseg * 8;

    const int lane = tid & 63;
    const int wv   = tid >> 6;
    const int wm   = (wv & 1) * 64;
    const int wn   = (wv >> 1) * 64;
    const int l15  = lane & 15;
    const int quad = lane >> 4;
    const int x0   = (quad ^ (l15 & 7)) * 8;

    int aoffs[4], boffs[4];
#pragma unroll
    for (int i = 0; i < 4; i++) {
        aoffs[i] = (wm + i * 16 + l15) * 64 + x0;
        boffs[i] = (wn + i * 16 + l15) * 64 + x0;
    }

    floatx4 acc[4][4];
#pragma unroll
    for (int i = 0; i < 4; i++)
#pragma unroll
        for (int j = 0; j < 4; j++) acc[i][j] = (floatx4){0.f, 0.f, 0.f, 0.f};

    for (int k0 = 0; k0 < F_; k0 += 64) {
#pragma unroll
        for (int w = 0; w < 4; w++) {
            gl_lds16(H   + aoff0 + (size_t)w * 32 * F_ + k0, &Asm2[(w * 256 + tid) * 8]);
            gl_lds16(w2t + boff0 + (size_t)w * 32 * F_ + k0, &Bsm2[(w * 256 + tid) * 8]);
        }
        __syncthreads();
        bf16x8 af[4], bfr[4];
#pragma unroll
        for (int i = 0; i < 4; i++) {
            af[i]  = *(const bf16x8*)&Asm2[aoffs[i]];
            bfr[i] = *(const bf16x8*)&Bsm2[boffs[i]];
        }
#pragma unroll
        for (int i = 0; i < 4; i++)
#pragma unroll
            for (int j = 0; j < 4; j++)
                acc[i][j] = __builtin_amdgcn_mfma_f32_16x16x32_bf16(af[i], bfr[j], acc[i][j], 0, 0, 0);
#pragma unroll
        for (int i = 0; i < 4; i++) {
            af[i]  = *(const bf16x8*)&Asm2[aoffs[i] ^ 32];
            bfr[i] = *(const bf16x8*)&Bsm2[boffs[i] ^ 32];
        }
#pragma unroll
        for (int i = 0; i < 4; i++)
#pragma unroll
            for (int j = 0; j < 4; j++)
                acc[i][j] = __builtin_amdgcn_mfma_f32_16x16x32_bf16(af[i], bfr[j], acc[i][j], 0, 0, 0);
        __syncthreads();
    }

    // epilogue: plain coalesced bf16 stores (combine kernel applies G and scatters)
    unsigned short* Xbe = xmlp + (size_t)be * KCAP * D_;
#pragma unroll
    for (int i = 0; i < 4; i++) {
#pragma unroll
        for (int r = 0; r < 4; r++) {
            int m = mt * 128 + wm + i * 16 + quad * 4 + r;
            unsigned short* orow = Xbe + (size_t)m * D_ + nt * 128;
#pragma unroll
            for (int j = 0; j < 4; j++)
                orow[wn + j * 16 + l15] = f2b(acc[i][j][r]);
        }
    }
}

// ---------------- 5. combine: out[b,s,:] = sum_e Pmap-hit G * xmlp-row (each token written once) -------
__global__ void combine_kernel(const unsigned short* __restrict__ xmlp, // [B*E][KCAP][D] bf16
                               const unsigned short* __restrict__ Pmap, // [B][S][E] slot+1
                               const float* __restrict__ G,             // [B*E][KCAP]
                               float* __restrict__ out) {               // [B][S][D] fp32
    int gid  = blockIdx.x * 256 + threadIdx.x;
    int wave = gid >> 6;                               // token id b*S+s
    int lane = gid & 63;
    int b = wave >> 10;
    float acc[16];
#pragma unroll
    for (int i = 0; i < 16; i++) acc[i] = 0.f;
    const unsigned short* pm = Pmap + (size_t)wave * E_;
#pragma unroll
    for (int e = 0; e < E_; e++) {
        int pe = pm[e];
        if (pe) {
            int beslot = (b * E_ + e) * KCAP + (pe - 1);
            float g = G[beslot];
            const unsigned short* rw = xmlp + (size_t)beslot * D_ + lane * 16;
            ushortx8 r0 = *(const ushortx8*)(rw);
            ushortx8 r1 = *(const ushortx8*)(rw + 8);
#pragma unroll
            for (int i = 0; i < 8; i++) {
                acc[i]     = fmaf(g, b2f(r0[i]), acc[i]);
                acc[8 + i] = fmaf(g, b2f(r1[i]), acc[8 + i]);
            }
        }
    }
    float* orow = out + (size_t)wave * D_ + lane * 16;
    ((float4*)orow)[0] = make_float4(acc[0],  acc[1],  acc[2],  acc[3]);
    ((float4*)orow)[1] = make_float4(acc[4],  acc[5],  acc[6],  acc[7]);
    ((float4*)orow)[2] = make_float4(acc[8],  acc[9],  acc[10], acc[11]);
    ((float4*)orow)[3] = make_float4(acc[12], acc[13], acc[14], acc[15]);
}

// ---------------- launch ----------------
extern "C" void kernel_launch(void* const* d_in, const int* in_sizes, int n_in,
                              void* d_out, int out_size, void* d_ws, size_t ws_size,
                              hipStream_t stream) {
    const float* x  = (const float*)d_in[0];
    const float* cw = (const float*)d_in[1];
    const float* w1 = (const float*)d_in[2];
    const float* w2 = (const float*)d_in[3];
    float* out = (float*)d_out;

    // workspace layout (bytes), total exactly 151,519,232:
    //   probs   @ 0         (0.26 MB)  [B][E][S] fp32
    //   Ibuf    @ 262144    (64 KB)
    //   Gbuf    @ 327680    (64 KB)
    //   Pmap    @ 393216    (128 KB)   [B][S][E] slot+1
    //   xb      @ 524288    (16.78 MB) x bf16
    //   w1t     @ 17301504  (33.55 MB) [E][F][D] bf16; DEAD after gemm1 -> xmlp aliases it
    //   w2t     @ 50855936  (33.55 MB) [E][D][F] bf16
    //   Hbuf    @ 84410368  (67.11 MB) [B*E][256][F] bf16
    char* ws = (char*)d_ws;
    float*          probs = (float*)(ws);
    int*            Ibuf  = (int*)(ws + 262144);
    float*          Gbuf  = (float*)(ws + 327680);
    unsigned short* Pmap  = (unsigned short*)(ws + 393216);
    unsigned short* xb    = (unsigned short*)(ws + 524288);
    unsigned short* w1t   = (unsigned short*)(ws + 17301504);
    unsigned short* xmlp  = w1t;                                 // alias: w1t dead after gemm1
    unsigned short* w2t   = (unsigned short*)(ws + 50855936);
    unsigned short* Hbuf  = (unsigned short*)(ws + 84410368);

    router_kernel<<<(B_ * S_ * 64) / 256, 256, 0, stream>>>(x, cw, probs, xb);
    prep_kernel<<<2 * 4096 + B_ * E_, 256, 0, stream>>>(w1, w2, w1t, w2t, probs, Ibuf, Gbuf, Pmap);
    gemm1_kernel<<<B_ * E_ * 2 * (F_ / 128), 256, 0, stream>>>(xb, w1t, Ibuf, Hbuf);
    gemm2_kernel<<<B_ * E_ * 2 * (D_ / 128), 256, 0, stream>>>(Hbuf, w2t, xmlp);
    combine_kernel<<<(B_ * S_ * 64) / 256, 256, 0, stream>>>(xmlp, Pmap, Gbuf, out);
}

// Round 8
// 353.913 us; speedup vs baseline: 1.0789x; 1.0789x over previous
//
#include <hip/hip_runtime.h>
#include <hip/hip_bf16.h>
#include <math.h>

// Problem constants (reference: B=8, S=1024, D=1024, E=8, F=2048, capacity 2 -> k=256)
#define B_   8
#define S_   1024
#define D_   1024
#define E_   8
#define F_   2048
#define KCAP 256

typedef __bf16 bf16x8 __attribute__((ext_vector_type(8)));
typedef float  floatx4 __attribute__((ext_vector_type(4)));
typedef unsigned short ushortx8 __attribute__((ext_vector_type(8)));

// ---- fp32 -> bf16 round-to-nearest-even (no NaN in this data) ----
__device__ __forceinline__ unsigned short f2b(float f) {
    union { float f; unsigned int u; } v; v.f = f;
    unsigned int u = v.u;
    u += 0x7fffu + ((u >> 16) & 1u);
    return (unsigned short)(u >> 16);
}
__device__ __forceinline__ float b2f(unsigned short u) {
    union { unsigned int u; float f; } v; v.u = ((unsigned)u) << 16; return v.f;
}

__device__ __forceinline__ void gl_lds16(const void* g, void* l) {
    __builtin_amdgcn_global_load_lds(
        (const __attribute__((address_space(1))) void*)g,
        (__attribute__((address_space(3))) void*)l, 16, 0, 0);
}

// sortable key: probs > 0 so float bits are monotonic; secondary index asc
// (larger (1023-s) wins ties -> smaller s, matching lax.top_k).
__device__ __forceinline__ unsigned long long topk_key(float p, int s) {
    return (((unsigned long long)__float_as_uint(p)) << 10) | (unsigned)(S_ - 1 - s);
}

// ---------------- 1. router: logits + softmax (fp32) + fused x->bf16 cast (vectorized) ----------------
// probs layout: [B][E][S] (transposed for per-(b,e) top-k). One wave per token; lane owns 4 consecutive d.
__global__ void router_kernel(const float* __restrict__ x, const float* __restrict__ cw,
                              float* __restrict__ probs, unsigned short* __restrict__ xb) {
    int gid  = blockIdx.x * 256 + threadIdx.x;
    int wave = gid >> 6;
    int lane = gid & 63;
    int b = wave >> 10;                                // S_=1024
    int s = wave & (S_ - 1);
    const float* xrow = x + ((size_t)b * S_ + s) * D_;
    unsigned short* xbrow = xb + ((size_t)b * S_ + s) * D_;
    float acc[E_];
#pragma unroll
    for (int e = 0; e < E_; e++) acc[e] = 0.f;
#pragma unroll
    for (int it = 0; it < D_ / 256; it++) {
        int i = it * 256 + lane * 4;
        float4 xv = *(const float4*)(xrow + i);
        ushort4 o;
        o.x = f2b(xv.x); o.y = f2b(xv.y); o.z = f2b(xv.z); o.w = f2b(xv.w);
        *(ushort4*)(xbrow + i) = o;                    // fused cast, 8B/lane stores
#pragma unroll
        for (int e = 0; e < E_; e++) {
            float4 wv = *(const float4*)(cw + e * D_ + i);   // 32KB table, L1/L2-resident
            acc[e] = fmaf(xv.x, wv.x, fmaf(xv.y, wv.y, fmaf(xv.z, wv.z, fmaf(xv.w, wv.w, acc[e]))));
        }
    }
#pragma unroll
    for (int e = 0; e < E_; e++) {
        float v = acc[e];
#pragma unroll
        for (int off = 32; off >= 1; off >>= 1) v += __shfl_down(v, off, 64);
        acc[e] = v;
    }
    if (lane == 0) {
        float m = acc[0];
#pragma unroll
        for (int e = 1; e < E_; e++) m = fmaxf(m, acc[e]);
        float sum = 0.f;
#pragma unroll
        for (int e = 0; e < E_; e++) { acc[e] = __expf(acc[e] - m); sum += acc[e]; }
        float inv = 1.f / sum;
#pragma unroll
        for (int e = 0; e < E_; e++) probs[((size_t)b * E_ + e) * S_ + s] = acc[e] * inv;
    }
}

// ---------------- 2. prep: persistent pipelined transposes + top-k (one launch) ----------------
// ROUND-7 LESSON: one-shot transpose blocks (load burst -> __syncthreads [drains vmcnt!]
// -> store burst -> endpgm [drains stores]) cap at ~1.5 TB/s regardless of tile size/ILP.
// Fix: 768 PERSISTENT blocks (3/CU), each loops ~11 tiles (stride 768 over 8192), with
// double-buffered LDS and register prefetch. Per iter: ds_write v(T); issue loads v(T+768);
// raw s_barrier preceded by lgkmcnt(0) ONLY (vmcnt NOT drained -> prefetch loads stay in
// flight across the barrier); ds_read cols + global_store. Stores drain once at endpgm.
// WAR ledger (double buffer, 1 barrier/iter): writes(n+2)->buf_n happen after barrier(n+1);
// all reads(n) of buf_n are lgkm-drained at barrier(n+1). RAW: reads(n) after barrier(n)
// see writes(n) (lgkm-drained at barrier(n)). sched_barrier(0) fences stop compiler
// migration across the raw barrier (round-1 lesson).
// Tile: 128 rows x 32 cols. Banks: write (rr+4seg+j)%32 2-way; read (8k+j+c)%32 2-way (free).
// grid: bid<64 topk (dispatched first); bid 64..831 transpose, tiles T = (bid-64) + k*768;
// T<4096 -> w1 [E][D][F]->w1t [E][F][D]; else w2 [E][F][D]->w2t [E][D][F].
union PrepSm {
    float tile[2][128][33];              // 33,792 B (transpose, double-buffered)
    unsigned long long keys[S_];         //  8,192 B (topk path)
};

#define PREP_DECODE(T, INP, OUTP, RV, CV, C0, R0) do { \
    int t_ = (T); \
    if (t_ < 4096) { \
        int e_ = t_ >> 9, tt_ = t_ & 511; \
        INP = w1 + (size_t)e_ * D_ * F_;  OUTP = w1t + (size_t)e_ * D_ * F_; \
        RV = D_; CV = F_; C0 = (tt_ & 63) * 32; R0 = (tt_ >> 6) * 128; \
    } else { \
        int t2_ = t_ - 4096; \
        int e_ = t2_ >> 9, tt_ = t2_ & 511; \
        INP = w2 + (size_t)e_ * D_ * F_;  OUTP = w2t + (size_t)e_ * D_ * F_; \
        RV = F_; CV = D_; C0 = (tt_ & 31) * 32; R0 = (tt_ >> 5) * 128; \
    } \
} while (0)

__global__ void prep_kernel(const float* __restrict__ w1, const float* __restrict__ w2,
                            unsigned short* __restrict__ w1t, unsigned short* __restrict__ w2t,
                            const float* __restrict__ probs, int* __restrict__ I,
                            float* __restrict__ G, unsigned short* __restrict__ Pmap) {
    const int bid = blockIdx.x;
    const int tid = threadIdx.x;
    __shared__ PrepSm sm;

    if (bid < B_ * E_) {
        // ---- top-k path (identical math to verified merged topk) ----
        const int be = bid;                           // 0..63
        const int b = be >> 3, e = be & 7;
        const float* rowp = probs + (size_t)be * S_;
#pragma unroll
        for (int q = 0; q < 4; q++) {
            const int s = q * 256 + tid;
            sm.keys[s] = topk_key(rowp[s], s);
            Pmap[((size_t)(b * S_ + s)) * E_ + e] = 0;
        }
        __syncthreads();
        unsigned long long my[4];
        int r[4] = {0, 0, 0, 0};
#pragma unroll
        for (int q = 0; q < 4; q++) my[q] = sm.keys[q * 256 + tid];
#pragma unroll 8
        for (int t = 0; t < S_; t++) {
            const unsigned long long kt = sm.keys[t]; // LDS broadcast
#pragma unroll
            for (int q = 0; q < 4; q++) r[q] += (kt > my[q]);
        }
#pragma unroll
        for (int q = 0; q < 4; q++) {
            if (r[q] < KCAP) {
                const int s = q * 256 + tid;
                I[be * KCAP + r[q]] = s;
                G[be * KCAP + r[q]] = rowp[s];
                Pmap[((size_t)(b * S_ + s)) * E_ + e] = (unsigned short)(r[q] + 1);
            }
        }
        return;
    }

    // ---- persistent pipelined transpose path ----
    const int tb   = bid - B_ * E_;                   // 0..767
    const int lrow = tid >> 3;                        // 0..31 (load role)
    const int seg  = tid & 7;                         // 0..7
    const int c    = tid >> 3;                        // 0..31 (store role)
    const int k    = tid & 7;                         // 0..7

    const float* inp; unsigned short* outp; int R, C, c0, r0;
    PREP_DECODE(tb, inp, outp, R, C, c0, r0);
    float4 v[4];
#pragma unroll
    for (int i = 0; i < 4; i++)
        v[i] = *(const float4*)(inp + (size_t)(r0 + lrow + i * 32) * C + c0 + seg * 4);

    int buf = 0;
    for (int T = tb; T < 8192; T += 768) {
        // save current tile's store coords before decode of next overwrites them
        unsigned short* oute = outp;
        const int Rr = R, cc0 = c0, rr0 = r0;

        // ds_write v(T) into sm.tile[buf]
#pragma unroll
        for (int i = 0; i < 4; i++) {
            const int rr = lrow + i * 32;
            sm.tile[buf][rr][seg * 4 + 0] = v[i].x;
            sm.tile[buf][rr][seg * 4 + 1] = v[i].y;
            sm.tile[buf][rr][seg * 4 + 2] = v[i].z;
            sm.tile[buf][rr][seg * 4 + 3] = v[i].w;
        }
        // prefetch v(T+768) -- loads stay in flight across the barrier (vmcnt not drained)
        if (T + 768 < 8192) {
            PREP_DECODE(T + 768, inp, outp, R, C, c0, r0);
#pragma unroll
            for (int i = 0; i < 4; i++)
                v[i] = *(const float4*)(inp + (size_t)(r0 + lrow + i * 32) * C + c0 + seg * 4);
        }
        // lgkm-only barrier (fenced against compiler migration)
        __builtin_amdgcn_sched_barrier(0);
        asm volatile("s_waitcnt lgkmcnt(0)" ::: "memory");
        __builtin_amdgcn_s_barrier();
        __builtin_amdgcn_sched_barrier(0);
        // read columns of tile[buf], store out-rows (256B contiguous per out-row)
#pragma unroll
        for (int srep = 0; srep < 2; srep++) {
            const int s8 = k + srep * 8;              // 0..15
            ushortx8 o;
#pragma unroll
            for (int j = 0; j < 8; j++) o[j] = f2b(sm.tile[buf][s8 * 8 + j][c]);
            *(ushortx8*)(oute + (size_t)(cc0 + c) * Rr + rr0 + s8 * 8) = o;
        }
        buf ^= 1;
    }
}

// ======== GEMM core notes (round-0 verified structure, ~880 TF) ========
// BK=64, 128x128 tile, 4 sweeps of 256 x 16B staging, bank-conflict-free via 16B-segment
// permutation seg_stored(c) = c ^ (row & 7) (verified: SQ_LDS_BANK_CONFLICT = 0).
// XCD swizzle: blockIdx % 8 selects e -> all tiles sharing w*t[e] on one XCD L2.
// NEGATIVE RESULTS (this session): 256^2 8-phase rewrite = 88 us / 32% Mfma vs 78 / 40%
// here (rounds 1-4); atomic-scatter combine fusion = +45 us on gemm2 (round 5; E*k/S = 2
// experts/token -> collisions are the norm). Launch-count reduction r0->r6 (8->5) = no
// wall change -> residual ~90 us is FIXED harness overhead; only kernel-sum matters.
// One-shot transpose blocks cap at 1.5 TB/s regardless of tile/ILP (rounds 6-7).

// ---------------- 3. GEMM1: H[be] = silu(gather(x, I[be]) @ w1[e]) ----------------
__global__ __launch_bounds__(256, 4) void gemm1_kernel(
    const unsigned short* __restrict__ xb,   // [B][S][D] bf16
    const unsigned short* __restrict__ w1t,  // [E][F][D] bf16
    const int* __restrict__ I,               // [B][E][KCAP]
    unsigned short* __restrict__ H)          // [B*E][KCAP][F] bf16
{
    const int g  = blockIdx.x;               // 2048 = 8 xcd * 8 b * 32 tiles
    const int e  = g & 7;                    // XCD id
    const int rr = g >> 3;
    const int b  = rr >> 5;
    const int t5 = rr & 31;
    const int be = b * 8 + e;
    const int mt = t5 & 1;          // 2 m-tiles (256/128)
    const int nt = t5 >> 1;         // 16 n-tiles (2048/128)
    const int tid = threadIdx.x;

    __shared__ __align__(16) unsigned short Asm[128 * 64];  // 16 KB
    __shared__ __align__(16) unsigned short Bsm[128 * 64];  // 16 KB
    __shared__ unsigned int ArowS[128];

    if (tid < 128) {
        int tok = I[(size_t)be * KCAP + mt * 128 + tid];
        ArowS[tid] = (unsigned)((b * S_ + tok) * D_);
    }
    __syncthreads();

    const int r8   = tid >> 3;                       // 0..31 (row within sweep)
    const int kseg = (tid & 7) ^ (r8 & 7);           // permuted 16B segment
    unsigned aoffW[4];
#pragma unroll
    for (int w = 0; w < 4; w++) aoffW[w] = ArowS[w * 32 + r8] + kseg * 8;
    const size_t boff0 = ((size_t)e * F_ + nt * 128 + r8) * D_ + kseg * 8;

    const int lane = tid & 63;
    const int wv   = tid >> 6;
    const int wm   = (wv & 1) * 64;
    const int wn   = (wv >> 1) * 64;
    const int l15  = lane & 15;
    const int quad = lane >> 4;
    const int x0   = (quad ^ (l15 & 7)) * 8;         // h=0 swizzled seg offset (elements)

    int aoffs[4], boffs[4];
#pragma unroll
    for (int i = 0; i < 4; i++) {
        aoffs[i] = (wm + i * 16 + l15) * 64 + x0;
        boffs[i] = (wn + i * 16 + l15) * 64 + x0;
    }

    floatx4 acc[4][4];
#pragma unroll
    for (int i = 0; i < 4; i++)
#pragma unroll
        for (int j = 0; j < 4; j++) acc[i][j] = (floatx4){0.f, 0.f, 0.f, 0.f};

    for (int k0 = 0; k0 < D_; k0 += 64) {
#pragma unroll
        for (int w = 0; w < 4; w++) {
            gl_lds16(xb  + aoffW[w] + k0,                    &Asm[(w * 256 + tid) * 8]);
            gl_lds16(w1t + boff0 + (size_t)w * 32 * D_ + k0, &Bsm[(w * 256 + tid) * 8]);
        }
        __syncthreads();
        bf16x8 af[4], bfr[4];
#pragma unroll
        for (int i = 0; i < 4; i++) {                 // k-half 0
            af[i]  = *(const bf16x8*)&Asm[aoffs[i]];
            bfr[i] = *(const bf16x8*)&Bsm[boffs[i]];
        }
#pragma unroll
        for (int i = 0; i < 4; i++)
#pragma unroll
            for (int j = 0; j < 4; j++)
                acc[i][j] = __builtin_amdgcn_mfma_f32_16x16x32_bf16(af[i], bfr[j], acc[i][j], 0, 0, 0);
#pragma unroll
        for (int i = 0; i < 4; i++) {                 // k-half 1: seg offset = x0 ^ 4 -> elem ^ 32
            af[i]  = *(const bf16x8*)&Asm[aoffs[i] ^ 32];
            bfr[i] = *(const bf16x8*)&Bsm[boffs[i] ^ 32];
        }
#pragma unroll
        for (int i = 0; i < 4; i++)
#pragma unroll
            for (int j = 0; j < 4; j++)
                acc[i][j] = __builtin_amdgcn_mfma_f32_16x16x32_bf16(af[i], bfr[j], acc[i][j], 0, 0, 0);
        __syncthreads();
    }

    // epilogue: silu -> H (bf16). C/D layout: row = quad*4+r, col = lane&15 (m89-verified)
    unsigned short* Hbe = H + (size_t)be * KCAP * F_;
#pragma unroll
    for (int i = 0; i < 4; i++) {
#pragma unroll
        for (int r = 0; r < 4; r++) {
            int m = mt * 128 + wm + i * 16 + quad * 4 + r;
            unsigned short* hrow = Hbe + (size_t)m * F_ + nt * 128;
#pragma unroll
            for (int j = 0; j < 4; j++) {
                float v = acc[i][j][r];
                float sv = v / (1.f + __expf(-v));
                hrow[wn + j * 16 + l15] = f2b(sv);
            }
        }
    }
}

// ---------------- 4. GEMM2: xmlp[be] = H[be] @ w2[e]  (bf16 out, plain stores) ----------------
__global__ __launch_bounds__(256, 4) void gemm2_kernel(
    const unsigned short* __restrict__ H,    // [B*E][KCAP][F] bf16
    const unsigned short* __restrict__ w2t,  // [E][D][F] bf16
    unsigned short* __restrict__ xmlp)       // [B*E][KCAP][D] bf16
{
    const int g  = blockIdx.x;               // 1024 = 8 xcd * 8 b * 16 tiles
    const int e  = g & 7;                    // XCD id
    const int rr = g >> 3;
    const int b  = rr >> 4;
    const int t4 = rr & 15;
    const int be = b * 8 + e;
    const int mt = t4 & 1;          // 2 m-tiles
    const int nt = t4 >> 1;         // 8 n-tiles (1024/128)
    const int tid = threadIdx.x;

    __shared__ __align__(16) unsigned short Asm2[128 * 64];
    __shared__ __align__(16) unsigned short Bsm2[128 * 64];

    const int r8   = tid >> 3;
    const int kseg = (tid & 7) ^ (r8 & 7);
    const size_t aoff0 = ((size_t)be * KCAP + mt * 128 + r8) * F_ + kseg * 8;
    const size_t boff0 = ((size_t)e * D_ + nt * 128 + r8) * F_ + kseg * 8;

    const int lane = tid & 63;
    const int wv   = tid >> 6;
    const int wm   = (wv & 1) * 64;
    const int wn   = (wv >> 1) * 64;
    const int l15  = lane & 15;
    const int quad = lane >> 4;
    const int x0   = (quad ^ (l15 & 7)) * 8;

    int aoffs[4], boffs[4];
#pragma unroll
    for (int i = 0; i < 4; i++) {
        aoffs[i] = (wm + i * 16 + l15) * 64 + x0;
        boffs[i] = (wn + i * 16 + l15) * 64 + x0;
    }

    floatx4 acc[4][4];
#pragma unroll
    for (int i = 0; i < 4; i++)
#pragma unroll
        for (int j = 0; j < 4; j++) acc[i][j] = (floatx4){0.f, 0.f, 0.f, 0.f};

    for (int k0 = 0; k0 < F_; k0 += 64) {
#pragma unroll
        for (int w = 0; w < 4; w++) {
            gl_lds16(H   + aoff0 + (size_t)w * 32 * F_ + k0, &Asm2[(w * 256 + tid) * 8]);
            gl_lds16(w2t + boff0 + (size_t)w * 32 * F_ + k0, &Bsm2[(w * 256 + tid) * 8]);
        }
        __syncthreads();
        bf16x8 af[4], bfr[4];
#pragma unroll
        for (int i = 0; i < 4; i++) {
            af[i]  = *(const bf16x8*)&Asm2[aoffs[i]];
            bfr[i] = *(const bf16x8*)&Bsm2[boffs[i]];
        }
#pragma unroll
        for (int i = 0; i < 4; i++)
#pragma unroll
            for (int j = 0; j < 4; j++)
                acc[i][j] = __builtin_amdgcn_mfma_f32_16x16x32_bf16(af[i], bfr[j], acc[i][j], 0, 0, 0);
#pragma unroll
        for (int i = 0; i < 4; i++) {
            af[i]  = *(const bf16x8*)&Asm2[aoffs[i] ^ 32];
            bfr[i] = *(const bf16x8*)&Bsm2[boffs[i] ^ 32];
        }
#pragma unroll
        for (int i = 0; i < 4; i++)
#pragma unroll
            for (int j = 0; j < 4; j++)
                acc[i][j] = __builtin_amdgcn_mfma_f32_16x16x32_bf16(af[i], bfr[j], acc[i][j], 0, 0, 0);
        __syncthreads();
    }

    // epilogue: plain coalesced bf16 stores (combine kernel applies G and scatters)
    unsigned short* Xbe = xmlp + (size_t)be * KCAP * D_;
#pragma unroll
    for (int i = 0; i < 4; i++) {
#pragma unroll
        for (int r = 0; r < 4; r++) {
            int m = mt * 128 + wm + i * 16 + quad * 4 + r;
            unsigned short* orow = Xbe + (size_t)m * D_ + nt * 128;
#pragma unroll
            for (int j = 0; j < 4; j++)
                orow[wn + j * 16 + l15] = f2b(acc[i][j][r]);
        }
    }
}

// ---------------- 5. combine: out[b,s,:] = sum_e Pmap-hit G * xmlp-row (each token written once) -------
__global__ void combine_kernel(const unsigned short* __restrict__ xmlp, // [B*E][KCAP][D] bf16
                               const unsigned short* __restrict__ Pmap, // [B][S][E] slot+1
                               const float* __restrict__ G,             // [B*E][KCAP]
                               float* __restrict__ out) {               // [B][S][D] fp32
    int gid  = blockIdx.x * 256 + threadIdx.x;
    int wave = gid >> 6;                               // token id b*S+s
    int lane = gid & 63;
    int b = wave >> 10;
    float acc[16];
#pragma unroll
    for (int i = 0; i < 16; i++) acc[i] = 0.f;
    const unsigned short* pm = Pmap + (size_t)wave * E_;
#pragma unroll
    for (int e = 0; e < E_; e++) {
        int pe = pm[e];
        if (pe) {
            int beslot = (b * E_ + e) * KCAP + (pe - 1);
            float g = G[beslot];
            const unsigned short* rw = xmlp + (size_t)beslot * D_ + lane * 16;
            ushortx8 r0 = *(const ushortx8*)(rw);
            ushortx8 r1 = *(const ushortx8*)(rw + 8);
#pragma unroll
            for (int i = 0; i < 8; i++) {
                acc[i]     = fmaf(g, b2f(r0[i]), acc[i]);
                acc[8 + i] = fmaf(g, b2f(r1[i]), acc[8 + i]);
            }
        }
    }
    float* orow = out + (size_t)wave * D_ + lane * 16;
    ((float4*)orow)[0] = make_float4(acc[0],  acc[1],  acc[2],  acc[3]);
    ((float4*)orow)[1] = make_float4(acc[4],  acc[5],  acc[6],  acc[7]);
    ((float4*)orow)[2] = make_float4(acc[8],  acc[9],  acc[10], acc[11]);
    ((float4*)orow)[3] = make_float4(acc[12], acc[13], acc[14], acc[15]);
}

// ---------------- launch ----------------
extern "C" void kernel_launch(void* const* d_in, const int* in_sizes, int n_in,
                              void* d_out, int out_size, void* d_ws, size_t ws_size,
                              hipStream_t stream) {
    const float* x  = (const float*)d_in[0];
    const float* cw = (const float*)d_in[1];
    const float* w1 = (const float*)d_in[2];
    const float* w2 = (const float*)d_in[3];
    float* out = (float*)d_out;

    // workspace layout (bytes), total exactly 151,519,232:
    //   probs   @ 0         (0.26 MB)  [B][E][S] fp32
    //   Ibuf    @ 262144    (64 KB)
    //   Gbuf    @ 327680    (64 KB)
    //   Pmap    @ 393216    (128 KB)   [B][S][E] slot+1
    //   xb      @ 524288    (16.78 MB) x bf16
    //   w1t     @ 17301504  (33.55 MB) [E][F][D] bf16; DEAD after gemm1 -> xmlp aliases it
    //   w2t     @ 50855936  (33.55 MB) [E][D][F] bf16
    //   Hbuf    @ 84410368  (67.11 MB) [B*E][256][F] bf16
    char* ws = (char*)d_ws;
    float*          probs = (float*)(ws);
    int*            Ibuf  = (int*)(ws + 262144);
    float*          Gbuf  = (float*)(ws + 327680);
    unsigned short* Pmap  = (unsigned short*)(ws + 393216);
    unsigned short* xb    = (unsigned short*)(ws + 524288);
    unsigned short* w1t   = (unsigned short*)(ws + 17301504);
    unsigned short* xmlp  = w1t;                                 // alias: w1t dead after gemm1
    unsigned short* w2t   = (unsigned short*)(ws + 50855936);
    unsigned short* Hbuf  = (unsigned short*)(ws + 84410368);

    router_kernel<<<(B_ * S_ * 64) / 256, 256, 0, stream>>>(x, cw, probs, xb);
    prep_kernel<<<B_ * E_ + 768, 256, 0, stream>>>(w1, w2, w1t, w2t, probs, Ibuf, Gbuf, Pmap);
    gemm1_kernel<<<B_ * E_ * 2 * (F_ / 128), 256, 0, stream>>>(xb, w1t, Ibuf, Hbuf);
    gemm2_kernel<<<B_ * E_ * 2 * (D_ / 128), 256, 0, stream>>>(Hbuf, w2t, xmlp);
    combine_kernel<<<(B_ * S_ * 64) / 256, 256, 0, stream>>>(xmlp, Pmap, Gbuf, out);
}